// Round 5
// baseline (1030.920 us; speedup 1.0000x reference)
//
#include <hip/hip_runtime.h>
#include <hip/hip_bf16.h>
#include <stdint.h>
#include <cstddef>

// Problem constants
#define BB  2
#define CC  512
#define TT  32
#define HWP 196   // H*W = 14*14
#define NH  8
#define KWIN 9
#define CID 64    // C / N
#define PPAD 4    // (K-1)/2
#define TP  40    // T + 2P
#define MTOT 12544  // BB*TT*HWP
#define NTOT 1536   // 3*CC (Q|K|V output channels)
#define VSLOT 224   // padded per-frame key slots (7*32)
#define GPITCH 72   // proj_gemm2 LDS row pitch (u16): 144 B, 16B-aligned
#define LOG2E 1.44269504f

typedef unsigned short u16;
typedef unsigned int   u32;
typedef __attribute__((ext_vector_type(8))) short short8;
typedef __attribute__((ext_vector_type(4))) float floatx4;

__device__ __forceinline__ u16 f2bf(float f) {
    u32 u = __float_as_uint(f);
    u32 r = (u + 0x7fffu + ((u >> 16) & 1u)) >> 16;
    return (u16)r;
}
__device__ __forceinline__ u32 pack2bf(float a, float b) {
    return (u32)f2bf(a) | ((u32)f2bf(b) << 16);
}
// Truncating pack: [hi16(b) : hi16(a)] in one v_perm_b32.
__device__ __forceinline__ u32 packtrunc(float a, float b) {
    return __builtin_amdgcn_perm(__float_as_uint(b), __float_as_uint(a), 0x07060302u);
}
// Raw hardware exp2 (v_exp_f32, 1 ulp); scores are nowhere near subnormal,
// OCML's denormal fixup is dead weight (verified: VALUBusy 54->25%).
__device__ __forceinline__ float fexp2(float x) {
    return __builtin_amdgcn_exp2f(x);
}

// ---------------------------------------------------------------------------
// Prep (fused): W concat fp32->bf16  +  pad-frame fill for K and Vtp.
// ---------------------------------------------------------------------------
__global__ __launch_bounds__(256) void prep_misc(
    const float* __restrict__ Wq, const float* __restrict__ Wk,
    const float* __restrict__ Wv, u16* __restrict__ Wbf,
    const float* __restrict__ bk, const float* __restrict__ bv,
    u16* __restrict__ Kout, u16* __restrict__ Vtp)
{
    int id = blockIdx.x * 256 + threadIdx.x;
    const int wtot = NTOT * CC / 2;                // 393,216 u32 (W)
    const int kper = 2 * NH * 8 * HWP * 32;        // 802,816 u32 (K pads)
    const int vper = 2 * NH * 8 * 64 * (VSLOT/2);  // 917,504 u32 (Vtp pads)
    if (id < wtot) {
        int c2 = id & 255;
        int oc = id >> 8;
        int kind = oc >> 9;
        int idx = oc & 511;
        const float* src = (kind == 0 ? Wq : (kind == 1 ? Wk : Wv)) + (size_t)idx * CC + c2 * 2;
        ((u32*)Wbf)[id] = pack2bf(src[0], src[1]);
    } else if (id < wtot + kper) {
        int i = id - wtot;
        int ci2 = i & 31; i >>= 5;
        int p = i % HWP;  i /= HWP;
        int fr = i & 7;   i >>= 3;
        int head = i & 7;
        int b = i >> 3;
        int tp = fr < 4 ? fr : fr + 32;
        const float* bias = bk + head * CID + ci2 * 2;
        size_t addr = (((size_t)(b * NH + head) * TP + tp) * HWP + p) * 32 + ci2;
        ((u32*)Kout)[addr] = pack2bf(bias[0], bias[1]);
    } else if (id < wtot + kper + vper) {
        int i = id - wtot - kper;
        int s2 = i % (VSLOT/2); i /= (VSLOT/2);
        int ci = i & 63; i >>= 6;
        int fr = i & 7;  i >>= 3;
        int head = i & 7;
        int b = i >> 3;
        int tp = fr < 4 ? fr : fr + 32;
        float bias = bv[head * CID + ci];
        size_t addr = (((size_t)(b * NH + head) * TP + tp) * 64 + ci) * (VSLOT/2) + s2;
        ((u32*)Vtp)[addr] = pack2bf(bias, bias);   // whole row = bias[ci]
    }
}

// ---------------------------------------------------------------------------
// Prep 2: transpose x[b][c][t][p] fp32 -> xt[(b*T+t)*HW+p][c] bf16.
// ---------------------------------------------------------------------------
__global__ __launch_bounds__(256) void transpose_x(
    const float* __restrict__ x, u16* __restrict__ xt)
{
    __shared__ float T[64 * 197];
    int bx = blockIdx.x;
    int ct = bx & 7; bx >>= 3;
    int t = bx & 31;
    int b = bx >> 5;
    int tid = threadIdx.x;
    const float* src = x + ((size_t)(b * CC + ct * 64) * TT + t) * HWP;
    for (int i = tid; i < 64 * HWP; i += 256) {
        int c = i / HWP;
        int p = i - c * HWP;
        T[c * 197 + p] = src[(size_t)c * (TT * HWP) + p];
    }
    __syncthreads();
    u16* dst = xt + (size_t)((b * TT + t) * HWP) * CC + ct * 64;
    for (int i = tid; i < HWP * 64; i += 256) {
        int p = i >> 6;
        int c = i & 63;
        dst[(size_t)p * CC + c] = f2bf(T[c * 197 + p]);
    }
}

// ---------------------------------------------------------------------------
// MFMA projection GEMM v2 (LDS-staged): Out^T[m,n] = xt[m,c].Wbf[n,c]+bias.
// ---------------------------------------------------------------------------
__global__ __launch_bounds__(512) void proj_gemm2(
    const u16* __restrict__ xt, const u16* __restrict__ Wbf,
    const float* __restrict__ bq, const float* __restrict__ bk,
    const float* __restrict__ bv,
    u16* __restrict__ Qout, u16* __restrict__ Kout, u16* __restrict__ Vplain)
{
    __shared__ u16 sA[128 * GPITCH];   // 18,432 B
    __shared__ u16 sB[256 * GPITCH];   // 36,864 B

    int bx = blockIdx.x;
    int nb = bx % 6;
    int mt = bx / 6;
    int tid = threadIdx.x;
    int wave = tid >> 6, lane = tid & 63, quad = lane >> 4, l15 = lane & 15;
    int wm = wave >> 2, wn = wave & 3;
    int mbase = mt * 128 + wm * 64;
    int nbase = nb * 256 + wn * 64;

    floatx4 acc[4][4];
    #pragma unroll
    for (int ms = 0; ms < 4; ms++)
        #pragma unroll
        for (int ns = 0; ns < 4; ns++)
            acc[ms][ns] = (floatx4){0.f, 0.f, 0.f, 0.f};

    const u16* agbase = xt + (size_t)(mt * 128) * CC;
    const u16* bgbase = Wbf + (size_t)(nb * 256) * CC;

    for (int kc = 0; kc < 8; kc++) {
        __syncthreads();
        // Stage A: 128 rows x 8 uint4 (64 u16) = 1024 chunks, 2/thread.
        #pragma unroll
        for (int it = 0; it < 2; it++) {
            int idx = it * 512 + tid;
            int row = idx >> 3, jj = idx & 7;
            uint4 v = *(const uint4*)(agbase + (size_t)row * CC + kc * 64 + jj * 8);
            *(uint4*)&sA[row * GPITCH + jj * 8] = v;
        }
        // Stage B: 256 rows x 8 uint4 = 2048 chunks, 4/thread.
        #pragma unroll
        for (int it = 0; it < 4; it++) {
            int idx = it * 512 + tid;
            int row = idx >> 3, jj = idx & 7;
            uint4 v = *(const uint4*)(bgbase + (size_t)row * CC + kc * 64 + jj * 8);
            *(uint4*)&sB[row * GPITCH + jj * 8] = v;
        }
        __syncthreads();

        #pragma unroll
        for (int kk = 0; kk < 2; kk++) {
            short8 af[4], bf[4];
            #pragma unroll
            for (int ms = 0; ms < 4; ms++)
                af[ms] = *(const short8*)&sA[(wm * 64 + ms * 16 + l15) * GPITCH + kk * 32 + quad * 8];
            #pragma unroll
            for (int ns = 0; ns < 4; ns++)
                bf[ns] = *(const short8*)&sB[(wn * 64 + ns * 16 + l15) * GPITCH + kk * 32 + quad * 8];
            #pragma unroll
            for (int ms = 0; ms < 4; ms++)
                #pragma unroll
                for (int ns = 0; ns < 4; ns++)
                    acc[ms][ns] = __builtin_amdgcn_mfma_f32_16x16x32_bf16(
                        af[ms], bf[ns], acc[ms][ns], 0, 0, 0);
        }
    }

    float biasv[4];
    #pragma unroll
    for (int ns = 0; ns < 4; ns++) {
        int n = nbase + ns * 16 + l15;
        int kind = n >> 9;
        int idx = n & 511;
        const float* bpb = kind == 0 ? bq : (kind == 1 ? bk : bv);
        biasv[ns] = bpb[idx];
    }

    #pragma unroll
    for (int ms = 0; ms < 4; ms++) {
        #pragma unroll
        for (int r = 0; r < 4; r++) {
            int m = mbase + ms * 16 + quad * 4 + r;
            int b = m / (TT * HWP);
            int rem = m - b * (TT * HWP);
            int t = rem / HWP;
            int p = rem - t * HWP;
            #pragma unroll
            for (int ns = 0; ns < 4; ns++) {
                int n = nbase + ns * 16 + l15;
                int kind = n >> 9;          // uniform across block (kind = nb>>1)
                int idx = n & 511;
                int head = idx >> 6;
                int ci = idx & 63;
                float val = acc[ms][ns][r] + biasv[ns];
                if (kind == 0) {
                    Qout[(((size_t)(b * NH + head) * TT + t) * HWP + p) * CID + ci]
                        = f2bf(val * LOG2E);
                } else if (kind == 1) {
                    Kout[(((size_t)(b * NH + head) * TP + (t + PPAD)) * HWP + p) * CID + ci]
                        = f2bf(val);
                } else {
                    Vplain[(((size_t)(b * NH + head) * TT + t) * HWP + p) * CID + ci]
                        = f2bf(val);
                }
            }
        }
    }
}

// ---------------------------------------------------------------------------
// Prep 4: Vplain [t][p][ci] (32 real frames) -> Vtp [tp][ci][slot(p)].
// ---------------------------------------------------------------------------
__global__ __launch_bounds__(256) void v_reformat(
    const u16* __restrict__ Vplain, u16* __restrict__ Vtp)
{
    __shared__ u16 T[HWP * 66];
    int bx = blockIdx.x;
    int t = bx & 31;
    int slab = bx >> 5;
    int tid = threadIdx.x;
    const u32* src = (const u32*)(Vplain + ((size_t)slab * TT + t) * (HWP * CID));
    for (int i = tid; i < HWP * 32; i += 256) {
        int p = i >> 5, c2 = i & 31;
        u32 v = src[i];
        T[p * 66 + c2 * 2]     = (u16)(v & 0xffffu);
        T[p * 66 + c2 * 2 + 1] = (u16)(v >> 16);
    }
    __syncthreads();
    u32* dst = (u32*)(Vtp + ((size_t)slab * TP + (t + PPAD)) * (64 * VSLOT));
    for (int i = tid; i < 64 * 98; i += 256) {
        int ci = i / 98;
        int s2 = i - ci * 98;
        int s = s2 * 2;
        int s5 = s & 31;
        int p0 = (s & ~31) | (((s5 >> 2) & 1) << 4) | ((s5 >> 3) << 2) | (s5 & 3);
        u32 lo = T[p0 * 66 + ci];
        u32 hi = T[(p0 + 1) * 66 + ci];
        dst[ci * (VSLOT / 2) + s2] = lo | (hi << 16);
    }
}

// ---------------------------------------------------------------------------
// MFMA flash attention v9: frame-split TLP. 8 waves (512 thr); wave-group
// g = wave>>2 computes frames 0-4 (g=0) or 5-8 (g=1) with the FULL 4-q-tile
// per-wave geometry (identical register profile to the verified v8). The
// softmax here has no running max — O and l are plain sums over frames, so
// groups combine exactly via LDS adds in the epilogue. Main loop stays
// barrier-free and LDS-free. Waves/SIMD 2 -> 4 for latency hiding.
// ---------------------------------------------------------------------------
__global__ __launch_bounds__(512, 4) void attn_mfma4(
    const float* __restrict__ x,
    const u16* __restrict__ Qb, const u16* __restrict__ Kb,
    const u16* __restrict__ Vtp, float* __restrict__ zout)
{
    __shared__ float eT[HWP * 66];    // 51,744 B — O accumulator / transpose
    __shared__ float lsum[HWP];       //    784 B — softmax denominators

    int i = blockIdx.x;
    int xcd = i & 7;
    int r = i >> 3;                        // 0..63
    int slab = ((r >= 32) ? 8 : 0) | xcd;  // slab pinned to one XCD
    int t = r & 31;
    int b = slab >> 3, n = slab & 7;

    int tid = threadIdx.x;
    int wave = tid >> 6;
    int g = wave >> 2;                 // frame group: 0 -> f 0..4, 1 -> f 5..8
    int wq = wave & 3;                 // q-tile role within group
    int lane = tid & 63;
    int quad = lane >> 4, l15 = lane & 15;

    const u16* kfr0 = Kb + (size_t)slab * (TP * HWP) * CID;
    const u16* vslab = Vtp + (size_t)slab * (TP * 64 * VSLOT);
    const float tmask = (quad == 0) ? 1.0f : 0.0f;

    // Persistent Q B-frags: tiles tg = wq + 4*j  (j = 0..3)
    short8 qf[4][2];
    #pragma unroll
    for (int j = 0; j < 4; j++) {
        int qrow = (wq + 4 * j) * 16 + l15;
        qrow = qrow < HWP ? qrow : (HWP - 1);
        const u16* qp = Qb + ((size_t)(slab * TT + t) * HWP + qrow) * CID;
        qf[j][0] = *(const short8*)(qp + quad * 8);
        qf[j][1] = *(const short8*)(qp + 32 + quad * 8);
    }

    floatx4 acc[4][4];
    floatx4 accl[4];
    #pragma unroll
    for (int j = 0; j < 4; j++) {
        #pragma unroll
        for (int cg = 0; cg < 4; cg++) acc[j][cg] = (floatx4){0.f, 0.f, 0.f, 0.f};
        accl[j] = (floatx4){0.f, 0.f, 0.f, 0.f};
    }

    union { u32 w[4]; short8 s; } ones;
    ones.w[0] = 0x3F803F80u; ones.w[1] = 0x3F803F80u;
    ones.w[2] = 0x3F803F80u; ones.w[3] = 0x3F803F80u;

    #define KLOAD(c, D00, D01, D10, D11) do {                                    \
        const u16* a0_ = kfr0 + (size_t)(rbase + (c) * 32 + l15) * CID + quad * 8;\
        const u16* a1_ = a0_ + (size_t)16 * CID;                                 \
        D00 = *(const short8*)a0_;  D01 = *(const short8*)(a0_ + 32);            \
        D10 = *(const short8*)a1_;  D11 = *(const short8*)(a1_ + 32);            \
    } while (0)

    #define KLOADTAIL(D00, D01) do {                                             \
        int g_ = rbase + 192 + l15;                                              \
        g_ = g_ < (TP * HWP - 1) ? g_ : (TP * HWP - 1);                          \
        const u16* a0_ = kfr0 + (size_t)g_ * CID + quad * 8;                     \
        D00 = *(const short8*)a0_;  D01 = *(const short8*)(a0_ + 32);            \
    } while (0)

    #define VLOAD(c, D0, D1, D2, D3) do {                                        \
        const u16* v_ = vfr + l15 * VSLOT + (c) * 32 + quad * 8;                 \
        D0 = *(const short8*)v_;                                                 \
        D1 = *(const short8*)(v_ + 16 * VSLOT);                                  \
        D2 = *(const short8*)(v_ + 32 * VSLOT);                                  \
        D3 = *(const short8*)(v_ + 48 * VSLOT);                                  \
    } while (0)

    #define CHUNK_FULL(K00, K01, K10, K11, V0, V1, V2, V3)                       \
        _Pragma("unroll")                                                        \
        for (int j = 0; j < 4; j++) {                                            \
            floatx4 sc0 = (floatx4){0.f, 0.f, 0.f, 0.f};                         \
            sc0 = __builtin_amdgcn_mfma_f32_16x16x32_bf16(K00, qf[j][0], sc0, 0, 0, 0); \
            sc0 = __builtin_amdgcn_mfma_f32_16x16x32_bf16(K01, qf[j][1], sc0, 0, 0, 0); \
            floatx4 sc1 = (floatx4){0.f, 0.f, 0.f, 0.f};                         \
            sc1 = __builtin_amdgcn_mfma_f32_16x16x32_bf16(K10, qf[j][0], sc1, 0, 0, 0); \
            sc1 = __builtin_amdgcn_mfma_f32_16x16x32_bf16(K11, qf[j][1], sc1, 0, 0, 0); \
            union { u32 w[4]; short8 s; } pf;                                    \
            pf.w[0] = packtrunc(fexp2(sc0[0]), fexp2(sc0[1]));                   \
            pf.w[1] = packtrunc(fexp2(sc0[2]), fexp2(sc0[3]));                   \
            pf.w[2] = packtrunc(fexp2(sc1[0]), fexp2(sc1[1]));                   \
            pf.w[3] = packtrunc(fexp2(sc1[2]), fexp2(sc1[3]));                   \
            acc[j][0] = __builtin_amdgcn_mfma_f32_16x16x32_bf16(pf.s, V0, acc[j][0], 0, 0, 0); \
            acc[j][1] = __builtin_amdgcn_mfma_f32_16x16x32_bf16(pf.s, V1, acc[j][1], 0, 0, 0); \
            acc[j][2] = __builtin_amdgcn_mfma_f32_16x16x32_bf16(pf.s, V2, acc[j][2], 0, 0, 0); \
            acc[j][3] = __builtin_amdgcn_mfma_f32_16x16x32_bf16(pf.s, V3, acc[j][3], 0, 0, 0); \
            accl[j]   = __builtin_amdgcn_mfma_f32_16x16x32_bf16(pf.s, ones.s, accl[j], 0, 0, 0); \
        }

    #define CHUNK_TAIL(K00, K01, V0, V1, V2, V3)                                 \
        _Pragma("unroll")                                                        \
        for (int j = 0; j < 4; j++) {                                            \
            floatx4 sc0 = (floatx4){0.f, 0.f, 0.f, 0.f};                         \
            sc0 = __builtin_amdgcn_mfma_f32_16x16x32_bf16(K00, qf[j][0], sc0, 0, 0, 0); \
            sc0 = __builtin_amdgcn_mfma_f32_16x16x32_bf16(K01, qf[j][1], sc0, 0, 0, 0); \
            union { u32 w[4]; short8 s; } pf;                                    \
            pf.w[0] = packtrunc(fexp2(sc0[0]) * tmask, fexp2(sc0[1]) * tmask);   \
            pf.w[1] = packtrunc(fexp2(sc0[2]) * tmask, fexp2(sc0[3]) * tmask);   \
            pf.w[2] = 0u;                                                        \
            pf.w[3] = 0u;                                                        \
            acc[j][0] = __builtin_amdgcn_mfma_f32_16x16x32_bf16(pf.s, V0, acc[j][0], 0, 0, 0); \
            acc[j][1] = __builtin_amdgcn_mfma_f32_16x16x32_bf16(pf.s, V1, acc[j][1], 0, 0, 0); \
            acc[j][2] = __builtin_amdgcn_mfma_f32_16x16x32_bf16(pf.s, V2, acc[j][2], 0, 0, 0); \
            acc[j][3] = __builtin_amdgcn_mfma_f32_16x16x32_bf16(pf.s, V3, acc[j][3], 0, 0, 0); \
            accl[j]   = __builtin_amdgcn_mfma_f32_16x16x32_bf16(pf.s, ones.s, accl[j], 0, 0, 0); \
        }

    int fbeg = g ? 5 : 0;
    int fend = g ? KWIN : 5;
    for (int f = fbeg; f < fend; f++) {
        int rbase = (t + f) * HWP;
        const u16* vfr = vslab + (size_t)(t + f) * (64 * VSLOT);

        short8 ka00, ka01, ka10, ka11, kb00, kb01, kb10, kb11;
        short8 va0, va1, va2, va3, vb0, vb1, vb2, vb3;

        // Software pipeline: load chunk c+1 (B/A alternating) before computing c.
        KLOAD(0, ka00, ka01, ka10, ka11);  VLOAD(0, va0, va1, va2, va3);
        KLOAD(1, kb00, kb01, kb10, kb11);  VLOAD(1, vb0, vb1, vb2, vb3);
        CHUNK_FULL(ka00, ka01, ka10, ka11, va0, va1, va2, va3);      // c=0
        KLOAD(2, ka00, ka01, ka10, ka11);  VLOAD(2, va0, va1, va2, va3);
        CHUNK_FULL(kb00, kb01, kb10, kb11, vb0, vb1, vb2, vb3);      // c=1
        KLOAD(3, kb00, kb01, kb10, kb11);  VLOAD(3, vb0, vb1, vb2, vb3);
        CHUNK_FULL(ka00, ka01, ka10, ka11, va0, va1, va2, va3);      // c=2
        KLOAD(4, ka00, ka01, ka10, ka11);  VLOAD(4, va0, va1, va2, va3);
        CHUNK_FULL(kb00, kb01, kb10, kb11, vb0, vb1, vb2, vb3);      // c=3
        KLOAD(5, kb00, kb01, kb10, kb11);  VLOAD(5, vb0, vb1, vb2, vb3);
        CHUNK_FULL(ka00, ka01, ka10, ka11, va0, va1, va2, va3);      // c=4
        KLOADTAIL(ka00, ka01);             VLOAD(6, va0, va1, va2, va3);
        CHUNK_FULL(kb00, kb01, kb10, kb11, vb0, vb1, vb2, vb3);      // c=5
        CHUNK_TAIL(ka00, ka01, va0, va1, va2, va3);                  // keys 192..195
    }

    #undef KLOAD
    #undef KLOADTAIL
    #undef VLOAD
    #undef CHUNK_FULL
    #undef CHUNK_TAIL

    // Epilogue: g0 writes raw O and l; g1 accumulates; normalize at store.
    if (g == 0) {
        #pragma unroll
        for (int j = 0; j < 4; j++) {
            int tg = wq + 4 * j;
            #pragma unroll
            for (int cg = 0; cg < 4; cg++) {
                #pragma unroll
                for (int rr = 0; rr < 4; rr++) {
                    int p = tg * 16 + quad * 4 + rr;
                    if (p < HWP)
                        eT[p * 66 + cg * 16 + l15] = acc[j][cg][rr];
                }
            }
            #pragma unroll
            for (int rr = 0; rr < 4; rr++) {
                int p = tg * 16 + quad * 4 + rr;
                if (p < HWP && l15 == 0)
                    lsum[p] = accl[j][rr];
            }
        }
    }
    __syncthreads();
    if (g == 1) {
        #pragma unroll
        for (int j = 0; j < 4; j++) {
            int tg = wq + 4 * j;
            #pragma unroll
            for (int cg = 0; cg < 4; cg++) {
                #pragma unroll
                for (int rr = 0; rr < 4; rr++) {
                    int p = tg * 16 + quad * 4 + rr;
                    if (p < HWP)
                        eT[p * 66 + cg * 16 + l15] += acc[j][cg][rr];
                }
            }
            #pragma unroll
            for (int rr = 0; rr < 4; rr++) {
                int p = tg * 16 + quad * 4 + rr;
                if (p < HWP && l15 == 0)
                    lsum[p] += accl[j][rr];
            }
        }
    }
    __syncthreads();

    {
        int p = tid >> 1;
        int ch = tid & 1;
        if (p < HWP) {
            float il = 1.0f / lsum[p];
            size_t base = ((size_t)(b * CC + n * CID + ch * 32) * TT + t) * HWP + p;
            for (int ci = 0; ci < 32; ci++) {
                size_t a = base + (size_t)ci * (TT * HWP);
                zout[a] = eT[p * 66 + ch * 32 + ci] * il + x[a];
            }
        }
    }
}

// ---------------------------------------------------------------------------
extern "C" void kernel_launch(void* const* d_in, const int* in_sizes, int n_in,
                              void* d_out, int out_size, void* d_ws, size_t ws_size,
                              hipStream_t stream) {
    const float* x  = (const float*)d_in[0];
    const float* Wq = (const float*)d_in[1];
    const float* bq = (const float*)d_in[2];
    const float* Wk = (const float*)d_in[3];
    const float* bk = (const float*)d_in[4];
    const float* Wv = (const float*)d_in[5];
    const float* bv = (const float*)d_in[6];
    float* z = (float*)d_out;

    // ws (bf16): Q, K, Vtp, W (~48.8 MB, proven). d_out scratch: xt + Vplain
    // (32 real frames) = exactly out_size*4 bytes (proven rounds 7-9).
    const size_t qElems   = (size_t)BB * NH * TT * HWP * CID;   // 6,422,528
    const size_t kElems   = (size_t)BB * NH * TP * HWP * CID;   // 8,028,160
    const size_t vtpElems = (size_t)BB * NH * TP * 64 * VSLOT;  // 9,175,040

    u16* Qw  = (u16*)d_ws;
    u16* Kw  = Qw + qElems;
    u16* Vtp = Kw + kElems;
    u16* Wb  = Vtp + vtpElems;
    u16* Xt  = (u16*)d_out;
    u16* Vpl = Xt + qElems;

    {
        const int wtot = NTOT * CC / 2;
        const int kper = 2 * NH * 8 * HWP * 32;
        const int vper = 2 * NH * 8 * 64 * (VSLOT / 2);
        prep_misc<<<(wtot + kper + vper + 255) / 256, 256, 0, stream>>>(
            Wq, Wk, Wv, Wb, bk, bv, Kw, Vtp);
    }
    transpose_x<<<BB * TT * 8, 256, 0, stream>>>(x, Xt);
    // 98 m-tiles (128 rows) x 6 n-tiles (256 cols), 512 threads = 8 waves
    proj_gemm2<<<98 * 6, 512, 0, stream>>>(Xt, Wb, bq, bk, bv, Qw, Kw, Vpl);
    v_reformat<<<BB * NH * TT, 256, 0, stream>>>(Vpl, Vtp);
    // 16 slabs * 32 t, 8 waves/block (frame-split g=0/1), XCD-swizzled;
    // 512 blocks = 2/CU -> 16 waves/CU (4/SIMD). Main loop barrier/LDS-free.
    attn_mfma4<<<512, 512, 0, stream>>>(x, Qw, Kw, Vtp, z);
}

// Round 7
// 254.344 us; speedup vs baseline: 4.0532x; 4.0532x over previous
//
#include <hip/hip_runtime.h>
#include <hip/hip_bf16.h>
#include <stdint.h>
#include <cstddef>

// Problem constants
#define BB  2
#define CC  512
#define TT  32
#define HWP 196   // H*W = 14*14
#define NH  8
#define KWIN 9
#define CID 64    // C / N
#define PPAD 4    // (K-1)/2
#define TP  40    // T + 2P
#define MTOT 12544  // BB*TT*HWP
#define NTOT 1536   // 3*CC (Q|K|V output channels)
#define VSLOT 224   // padded per-frame key slots (7*32)
#define GPITCH 72   // proj_gemm2 LDS row pitch (u16): 144 B, 16B-aligned
#define LOG2E 1.44269504f

typedef unsigned short u16;
typedef unsigned int   u32;
typedef __attribute__((ext_vector_type(8))) short short8;
typedef __attribute__((ext_vector_type(4))) float floatx4;

__device__ __forceinline__ u16 f2bf(float f) {
    u32 u = __float_as_uint(f);
    u32 r = (u + 0x7fffu + ((u >> 16) & 1u)) >> 16;
    return (u16)r;
}
__device__ __forceinline__ u32 pack2bf(float a, float b) {
    return (u32)f2bf(a) | ((u32)f2bf(b) << 16);
}
// Truncating pack: [hi16(b) : hi16(a)] in one v_perm_b32.
__device__ __forceinline__ u32 packtrunc(float a, float b) {
    return __builtin_amdgcn_perm(__float_as_uint(b), __float_as_uint(a), 0x07060302u);
}
// Raw hardware exp2 (v_exp_f32, 1 ulp); scores are nowhere near subnormal,
// OCML's denormal fixup is dead weight (verified: VALUBusy 54->25%).
__device__ __forceinline__ float fexp2(float x) {
    return __builtin_amdgcn_exp2f(x);
}

// ---------------------------------------------------------------------------
// Prep (fused): W concat fp32->bf16  +  pad-frame fill for K and Vtp.
// ---------------------------------------------------------------------------
__global__ __launch_bounds__(256) void prep_misc(
    const float* __restrict__ Wq, const float* __restrict__ Wk,
    const float* __restrict__ Wv, u16* __restrict__ Wbf,
    const float* __restrict__ bk, const float* __restrict__ bv,
    u16* __restrict__ Kout, u16* __restrict__ Vtp)
{
    int id = blockIdx.x * 256 + threadIdx.x;
    const int wtot = NTOT * CC / 2;                // 393,216 u32 (W)
    const int kper = 2 * NH * 8 * HWP * 32;        // 802,816 u32 (K pads)
    const int vper = 2 * NH * 8 * 64 * (VSLOT/2);  // 917,504 u32 (Vtp pads)
    if (id < wtot) {
        int c2 = id & 255;
        int oc = id >> 8;
        int kind = oc >> 9;
        int idx = oc & 511;
        const float* src = (kind == 0 ? Wq : (kind == 1 ? Wk : Wv)) + (size_t)idx * CC + c2 * 2;
        ((u32*)Wbf)[id] = pack2bf(src[0], src[1]);
    } else if (id < wtot + kper) {
        int i = id - wtot;
        int ci2 = i & 31; i >>= 5;
        int p = i % HWP;  i /= HWP;
        int fr = i & 7;   i >>= 3;
        int head = i & 7;
        int b = i >> 3;
        int tp = fr < 4 ? fr : fr + 32;
        const float* bias = bk + head * CID + ci2 * 2;
        size_t addr = (((size_t)(b * NH + head) * TP + tp) * HWP + p) * 32 + ci2;
        ((u32*)Kout)[addr] = pack2bf(bias[0], bias[1]);
    } else if (id < wtot + kper + vper) {
        int i = id - wtot - kper;
        int s2 = i % (VSLOT/2); i /= (VSLOT/2);
        int ci = i & 63; i >>= 6;
        int fr = i & 7;  i >>= 3;
        int head = i & 7;
        int b = i >> 3;
        int tp = fr < 4 ? fr : fr + 32;
        float bias = bv[head * CID + ci];
        size_t addr = (((size_t)(b * NH + head) * TP + tp) * 64 + ci) * (VSLOT/2) + s2;
        ((u32*)Vtp)[addr] = pack2bf(bias, bias);   // whole row = bias[ci]
    }
}

// ---------------------------------------------------------------------------
// Prep 2: transpose x[b][c][t][p] fp32 -> xt[(b*T+t)*HW+p][c] bf16.
// ---------------------------------------------------------------------------
__global__ __launch_bounds__(256) void transpose_x(
    const float* __restrict__ x, u16* __restrict__ xt)
{
    __shared__ float T[64 * 197];
    int bx = blockIdx.x;
    int ct = bx & 7; bx >>= 3;
    int t = bx & 31;
    int b = bx >> 5;
    int tid = threadIdx.x;
    const float* src = x + ((size_t)(b * CC + ct * 64) * TT + t) * HWP;
    for (int i = tid; i < 64 * HWP; i += 256) {
        int c = i / HWP;
        int p = i - c * HWP;
        T[c * 197 + p] = src[(size_t)c * (TT * HWP) + p];
    }
    __syncthreads();
    u16* dst = xt + (size_t)((b * TT + t) * HWP) * CC + ct * 64;
    for (int i = tid; i < HWP * 64; i += 256) {
        int p = i >> 6;
        int c = i & 63;
        dst[(size_t)p * CC + c] = f2bf(T[c * 197 + p]);
    }
}

// ---------------------------------------------------------------------------
// MFMA projection GEMM v2 (LDS-staged): Out^T[m,n] = xt[m,c].Wbf[n,c]+bias.
// ---------------------------------------------------------------------------
__global__ __launch_bounds__(512) void proj_gemm2(
    const u16* __restrict__ xt, const u16* __restrict__ Wbf,
    const float* __restrict__ bq, const float* __restrict__ bk,
    const float* __restrict__ bv,
    u16* __restrict__ Qout, u16* __restrict__ Kout, u16* __restrict__ Vplain)
{
    __shared__ u16 sA[128 * GPITCH];   // 18,432 B
    __shared__ u16 sB[256 * GPITCH];   // 36,864 B

    int bx = blockIdx.x;
    int nb = bx % 6;
    int mt = bx / 6;
    int tid = threadIdx.x;
    int wave = tid >> 6, lane = tid & 63, quad = lane >> 4, l15 = lane & 15;
    int wm = wave >> 2, wn = wave & 3;
    int mbase = mt * 128 + wm * 64;
    int nbase = nb * 256 + wn * 64;

    floatx4 acc[4][4];
    #pragma unroll
    for (int ms = 0; ms < 4; ms++)
        #pragma unroll
        for (int ns = 0; ns < 4; ns++)
            acc[ms][ns] = (floatx4){0.f, 0.f, 0.f, 0.f};

    const u16* agbase = xt + (size_t)(mt * 128) * CC;
    const u16* bgbase = Wbf + (size_t)(nb * 256) * CC;

    for (int kc = 0; kc < 8; kc++) {
        __syncthreads();
        // Stage A: 128 rows x 8 uint4 (64 u16) = 1024 chunks, 2/thread.
        #pragma unroll
        for (int it = 0; it < 2; it++) {
            int idx = it * 512 + tid;
            int row = idx >> 3, jj = idx & 7;
            uint4 v = *(const uint4*)(agbase + (size_t)row * CC + kc * 64 + jj * 8);
            *(uint4*)&sA[row * GPITCH + jj * 8] = v;
        }
        // Stage B: 256 rows x 8 uint4 = 2048 chunks, 4/thread.
        #pragma unroll
        for (int it = 0; it < 4; it++) {
            int idx = it * 512 + tid;
            int row = idx >> 3, jj = idx & 7;
            uint4 v = *(const uint4*)(bgbase + (size_t)row * CC + kc * 64 + jj * 8);
            *(uint4*)&sB[row * GPITCH + jj * 8] = v;
        }
        __syncthreads();

        #pragma unroll
        for (int kk = 0; kk < 2; kk++) {
            short8 af[4], bf[4];
            #pragma unroll
            for (int ms = 0; ms < 4; ms++)
                af[ms] = *(const short8*)&sA[(wm * 64 + ms * 16 + l15) * GPITCH + kk * 32 + quad * 8];
            #pragma unroll
            for (int ns = 0; ns < 4; ns++)
                bf[ns] = *(const short8*)&sB[(wn * 64 + ns * 16 + l15) * GPITCH + kk * 32 + quad * 8];
            #pragma unroll
            for (int ms = 0; ms < 4; ms++)
                #pragma unroll
                for (int ns = 0; ns < 4; ns++)
                    acc[ms][ns] = __builtin_amdgcn_mfma_f32_16x16x32_bf16(
                        af[ms], bf[ns], acc[ms][ns], 0, 0, 0);
        }
    }

    float biasv[4];
    #pragma unroll
    for (int ns = 0; ns < 4; ns++) {
        int n = nbase + ns * 16 + l15;
        int kind = n >> 9;
        int idx = n & 511;
        const float* bpb = kind == 0 ? bq : (kind == 1 ? bk : bv);
        biasv[ns] = bpb[idx];
    }

    #pragma unroll
    for (int ms = 0; ms < 4; ms++) {
        #pragma unroll
        for (int r = 0; r < 4; r++) {
            int m = mbase + ms * 16 + quad * 4 + r;
            int b = m / (TT * HWP);
            int rem = m - b * (TT * HWP);
            int t = rem / HWP;
            int p = rem - t * HWP;
            #pragma unroll
            for (int ns = 0; ns < 4; ns++) {
                int n = nbase + ns * 16 + l15;
                int kind = n >> 9;          // uniform across block (kind = nb>>1)
                int idx = n & 511;
                int head = idx >> 6;
                int ci = idx & 63;
                float val = acc[ms][ns][r] + biasv[ns];
                if (kind == 0) {
                    Qout[(((size_t)(b * NH + head) * TT + t) * HWP + p) * CID + ci]
                        = f2bf(val * LOG2E);
                } else if (kind == 1) {
                    Kout[(((size_t)(b * NH + head) * TP + (t + PPAD)) * HWP + p) * CID + ci]
                        = f2bf(val);
                } else {
                    Vplain[(((size_t)(b * NH + head) * TT + t) * HWP + p) * CID + ci]
                        = f2bf(val);
                }
            }
        }
    }
}

// ---------------------------------------------------------------------------
// Prep 4: Vplain [t][p][ci] (32 real frames) -> Vtp [tp][ci][slot(p)].
// ---------------------------------------------------------------------------
__global__ __launch_bounds__(256) void v_reformat(
    const u16* __restrict__ Vplain, u16* __restrict__ Vtp)
{
    __shared__ u16 T[HWP * 66];
    int bx = blockIdx.x;
    int t = bx & 31;
    int slab = bx >> 5;
    int tid = threadIdx.x;
    const u32* src = (const u32*)(Vplain + ((size_t)slab * TT + t) * (HWP * CID));
    for (int i = tid; i < HWP * 32; i += 256) {
        int p = i >> 5, c2 = i & 31;
        u32 v = src[i];
        T[p * 66 + c2 * 2]     = (u16)(v & 0xffffu);
        T[p * 66 + c2 * 2 + 1] = (u16)(v >> 16);
    }
    __syncthreads();
    u32* dst = (u32*)(Vtp + ((size_t)slab * TP + (t + PPAD)) * (64 * VSLOT));
    for (int i = tid; i < 64 * 98; i += 256) {
        int ci = i / 98;
        int s2 = i - ci * 98;
        int s = s2 * 2;
        int s5 = s & 31;
        int p0 = (s & ~31) | (((s5 >> 2) & 1) << 4) | ((s5 >> 3) << 2) | (s5 & 3);
        u32 lo = T[p0 * 66 + ci];
        u32 hi = T[(p0 + 1) * 66 + ci];
        dst[ci * (VSLOT / 2) + s2] = lo | (hi << 16);
    }
}

// ---------------------------------------------------------------------------
// MFMA flash attention v9b: frame-split TLP (R4 design), launch-bound FIX.
// On this hipcc, __launch_bounds__(512,4) caps VGPR at 64 (observed R1/R2/R5
// — CUDA-style min-BLOCKS semantics: 4 blk x 8 waves = 32 waves/CU -> 64
// VGPR) which spilled this 128-VGPR kernel catastrophically (R5: 933 us,
// 4 GB scratch traffic). (512,2) -> 16 waves/CU -> 128-VGPR budget: the
// intended 2 blocks/CU, 4 waves/SIMD.
// ---------------------------------------------------------------------------
__global__ __launch_bounds__(512, 2) void attn_mfma4(
    const float* __restrict__ x,
    const u16* __restrict__ Qb, const u16* __restrict__ Kb,
    const u16* __restrict__ Vtp, float* __restrict__ zout)
{
    __shared__ float eT[HWP * 66];    // 51,744 B — O accumulator / transpose
    __shared__ float lsum[HWP];       //    784 B — softmax denominators

    int i = blockIdx.x;
    int xcd = i & 7;
    int r = i >> 3;                        // 0..63
    int slab = ((r >= 32) ? 8 : 0) | xcd;  // slab pinned to one XCD
    int t = r & 31;
    int b = slab >> 3, n = slab & 7;

    int tid = threadIdx.x;
    int wave = tid >> 6;
    int g = wave >> 2;                 // frame group: 0 -> f 0..4, 1 -> f 5..8
    int wq = wave & 3;                 // q-tile role within group
    int lane = tid & 63;
    int quad = lane >> 4, l15 = lane & 15;

    const u16* kfr0 = Kb + (size_t)slab * (TP * HWP) * CID;
    const u16* vslab = Vtp + (size_t)slab * (TP * 64 * VSLOT);
    const float tmask = (quad == 0) ? 1.0f : 0.0f;

    // Persistent Q B-frags: tiles tg = wq + 4*j  (j = 0..3)
    short8 qf[4][2];
    #pragma unroll
    for (int j = 0; j < 4; j++) {
        int qrow = (wq + 4 * j) * 16 + l15;
        qrow = qrow < HWP ? qrow : (HWP - 1);
        const u16* qp = Qb + ((size_t)(slab * TT + t) * HWP + qrow) * CID;
        qf[j][0] = *(const short8*)(qp + quad * 8);
        qf[j][1] = *(const short8*)(qp + 32 + quad * 8);
    }

    floatx4 acc[4][4];
    floatx4 accl[4];
    #pragma unroll
    for (int j = 0; j < 4; j++) {
        #pragma unroll
        for (int cg = 0; cg < 4; cg++) acc[j][cg] = (floatx4){0.f, 0.f, 0.f, 0.f};
        accl[j] = (floatx4){0.f, 0.f, 0.f, 0.f};
    }

    union { u32 w[4]; short8 s; } ones;
    ones.w[0] = 0x3F803F80u; ones.w[1] = 0x3F803F80u;
    ones.w[2] = 0x3F803F80u; ones.w[3] = 0x3F803F80u;

    #define KLOAD(c, D00, D01, D10, D11) do {                                    \
        const u16* a0_ = kfr0 + (size_t)(rbase + (c) * 32 + l15) * CID + quad * 8;\
        const u16* a1_ = a0_ + (size_t)16 * CID;                                 \
        D00 = *(const short8*)a0_;  D01 = *(const short8*)(a0_ + 32);            \
        D10 = *(const short8*)a1_;  D11 = *(const short8*)(a1_ + 32);            \
    } while (0)

    #define KLOADTAIL(D00, D01) do {                                             \
        int g_ = rbase + 192 + l15;                                              \
        g_ = g_ < (TP * HWP - 1) ? g_ : (TP * HWP - 1);                          \
        const u16* a0_ = kfr0 + (size_t)g_ * CID + quad * 8;                     \
        D00 = *(const short8*)a0_;  D01 = *(const short8*)(a0_ + 32);            \
    } while (0)

    #define VLOAD(c, D0, D1, D2, D3) do {                                        \
        const u16* v_ = vfr + l15 * VSLOT + (c) * 32 + quad * 8;                 \
        D0 = *(const short8*)v_;                                                 \
        D1 = *(const short8*)(v_ + 16 * VSLOT);                                  \
        D2 = *(const short8*)(v_ + 32 * VSLOT);                                  \
        D3 = *(const short8*)(v_ + 48 * VSLOT);                                  \
    } while (0)

    #define CHUNK_FULL(K00, K01, K10, K11, V0, V1, V2, V3)                       \
        _Pragma("unroll")                                                        \
        for (int j = 0; j < 4; j++) {                                            \
            floatx4 sc0 = (floatx4){0.f, 0.f, 0.f, 0.f};                         \
            sc0 = __builtin_amdgcn_mfma_f32_16x16x32_bf16(K00, qf[j][0], sc0, 0, 0, 0); \
            sc0 = __builtin_amdgcn_mfma_f32_16x16x32_bf16(K01, qf[j][1], sc0, 0, 0, 0); \
            floatx4 sc1 = (floatx4){0.f, 0.f, 0.f, 0.f};                         \
            sc1 = __builtin_amdgcn_mfma_f32_16x16x32_bf16(K10, qf[j][0], sc1, 0, 0, 0); \
            sc1 = __builtin_amdgcn_mfma_f32_16x16x32_bf16(K11, qf[j][1], sc1, 0, 0, 0); \
            union { u32 w[4]; short8 s; } pf;                                    \
            pf.w[0] = packtrunc(fexp2(sc0[0]), fexp2(sc0[1]));                   \
            pf.w[1] = packtrunc(fexp2(sc0[2]), fexp2(sc0[3]));                   \
            pf.w[2] = packtrunc(fexp2(sc1[0]), fexp2(sc1[1]));                   \
            pf.w[3] = packtrunc(fexp2(sc1[2]), fexp2(sc1[3]));                   \
            acc[j][0] = __builtin_amdgcn_mfma_f32_16x16x32_bf16(pf.s, V0, acc[j][0], 0, 0, 0); \
            acc[j][1] = __builtin_amdgcn_mfma_f32_16x16x32_bf16(pf.s, V1, acc[j][1], 0, 0, 0); \
            acc[j][2] = __builtin_amdgcn_mfma_f32_16x16x32_bf16(pf.s, V2, acc[j][2], 0, 0, 0); \
            acc[j][3] = __builtin_amdgcn_mfma_f32_16x16x32_bf16(pf.s, V3, acc[j][3], 0, 0, 0); \
            accl[j]   = __builtin_amdgcn_mfma_f32_16x16x32_bf16(pf.s, ones.s, accl[j], 0, 0, 0); \
        }

    #define CHUNK_TAIL(K00, K01, V0, V1, V2, V3)                                 \
        _Pragma("unroll")                                                        \
        for (int j = 0; j < 4; j++) {                                            \
            floatx4 sc0 = (floatx4){0.f, 0.f, 0.f, 0.f};                         \
            sc0 = __builtin_amdgcn_mfma_f32_16x16x32_bf16(K00, qf[j][0], sc0, 0, 0, 0); \
            sc0 = __builtin_amdgcn_mfma_f32_16x16x32_bf16(K01, qf[j][1], sc0, 0, 0, 0); \
            union { u32 w[4]; short8 s; } pf;                                    \
            pf.w[0] = packtrunc(fexp2(sc0[0]) * tmask, fexp2(sc0[1]) * tmask);   \
            pf.w[1] = packtrunc(fexp2(sc0[2]) * tmask, fexp2(sc0[3]) * tmask);   \
            pf.w[2] = 0u;                                                        \
            pf.w[3] = 0u;                                                        \
            acc[j][0] = __builtin_amdgcn_mfma_f32_16x16x32_bf16(pf.s, V0, acc[j][0], 0, 0, 0); \
            acc[j][1] = __builtin_amdgcn_mfma_f32_16x16x32_bf16(pf.s, V1, acc[j][1], 0, 0, 0); \
            acc[j][2] = __builtin_amdgcn_mfma_f32_16x16x32_bf16(pf.s, V2, acc[j][2], 0, 0, 0); \
            acc[j][3] = __builtin_amdgcn_mfma_f32_16x16x32_bf16(pf.s, V3, acc[j][3], 0, 0, 0); \
            accl[j]   = __builtin_amdgcn_mfma_f32_16x16x32_bf16(pf.s, ones.s, accl[j], 0, 0, 0); \
        }

    int fbeg = g ? 5 : 0;
    int fend = g ? KWIN : 5;
    for (int f = fbeg; f < fend; f++) {
        int rbase = (t + f) * HWP;
        const u16* vfr = vslab + (size_t)(t + f) * (64 * VSLOT);

        short8 ka00, ka01, ka10, ka11, kb00, kb01, kb10, kb11;
        short8 va0, va1, va2, va3, vb0, vb1, vb2, vb3;

        // Software pipeline: load chunk c+1 (B/A alternating) before computing c.
        KLOAD(0, ka00, ka01, ka10, ka11);  VLOAD(0, va0, va1, va2, va3);
        KLOAD(1, kb00, kb01, kb10, kb11);  VLOAD(1, vb0, vb1, vb2, vb3);
        CHUNK_FULL(ka00, ka01, ka10, ka11, va0, va1, va2, va3);      // c=0
        KLOAD(2, ka00, ka01, ka10, ka11);  VLOAD(2, va0, va1, va2, va3);
        CHUNK_FULL(kb00, kb01, kb10, kb11, vb0, vb1, vb2, vb3);      // c=1
        KLOAD(3, kb00, kb01, kb10, kb11);  VLOAD(3, vb0, vb1, vb2, vb3);
        CHUNK_FULL(ka00, ka01, ka10, ka11, va0, va1, va2, va3);      // c=2
        KLOAD(4, ka00, ka01, ka10, ka11);  VLOAD(4, va0, va1, va2, va3);
        CHUNK_FULL(kb00, kb01, kb10, kb11, vb0, vb1, vb2, vb3);      // c=3
        KLOAD(5, kb00, kb01, kb10, kb11);  VLOAD(5, vb0, vb1, vb2, vb3);
        CHUNK_FULL(ka00, ka01, ka10, ka11, va0, va1, va2, va3);      // c=4
        KLOADTAIL(ka00, ka01);             VLOAD(6, va0, va1, va2, va3);
        CHUNK_FULL(kb00, kb01, kb10, kb11, vb0, vb1, vb2, vb3);      // c=5
        CHUNK_TAIL(ka00, ka01, va0, va1, va2, va3);                  // keys 192..195
    }

    #undef KLOAD
    #undef KLOADTAIL
    #undef VLOAD
    #undef CHUNK_FULL
    #undef CHUNK_TAIL

    // Epilogue: g0 writes raw O and l; g1 accumulates; normalize at store.
    if (g == 0) {
        #pragma unroll
        for (int j = 0; j < 4; j++) {
            int tg = wq + 4 * j;
            #pragma unroll
            for (int cg = 0; cg < 4; cg++) {
                #pragma unroll
                for (int rr = 0; rr < 4; rr++) {
                    int p = tg * 16 + quad * 4 + rr;
                    if (p < HWP)
                        eT[p * 66 + cg * 16 + l15] = acc[j][cg][rr];
                }
            }
            #pragma unroll
            for (int rr = 0; rr < 4; rr++) {
                int p = tg * 16 + quad * 4 + rr;
                if (p < HWP && l15 == 0)
                    lsum[p] = accl[j][rr];
            }
        }
    }
    __syncthreads();
    if (g == 1) {
        #pragma unroll
        for (int j = 0; j < 4; j++) {
            int tg = wq + 4 * j;
            #pragma unroll
            for (int cg = 0; cg < 4; cg++) {
                #pragma unroll
                for (int rr = 0; rr < 4; rr++) {
                    int p = tg * 16 + quad * 4 + rr;
                    if (p < HWP)
                        eT[p * 66 + cg * 16 + l15] += acc[j][cg][rr];
                }
            }
            #pragma unroll
            for (int rr = 0; rr < 4; rr++) {
                int p = tg * 16 + quad * 4 + rr;
                if (p < HWP && l15 == 0)
                    lsum[p] += accl[j][rr];
            }
        }
    }
    __syncthreads();

    {
        int p = tid >> 1;
        int ch = tid & 1;
        if (p < HWP) {
            float il = 1.0f / lsum[p];
            size_t base = ((size_t)(b * CC + n * CID + ch * 32) * TT + t) * HWP + p;
            for (int ci = 0; ci < 32; ci++) {
                size_t a = base + (size_t)ci * (TT * HWP);
                zout[a] = eT[p * 66 + ch * 32 + ci] * il + x[a];
            }
        }
    }
}

// ---------------------------------------------------------------------------
extern "C" void kernel_launch(void* const* d_in, const int* in_sizes, int n_in,
                              void* d_out, int out_size, void* d_ws, size_t ws_size,
                              hipStream_t stream) {
    const float* x  = (const float*)d_in[0];
    const float* Wq = (const float*)d_in[1];
    const float* bq = (const float*)d_in[2];
    const float* Wk = (const float*)d_in[3];
    const float* bk = (const float*)d_in[4];
    const float* Wv = (const float*)d_in[5];
    const float* bv = (const float*)d_in[6];
    float* z = (float*)d_out;

    // ws (bf16): Q, K, Vtp, W (~48.8 MB, proven). d_out scratch: xt + Vplain
    // (32 real frames) = exactly out_size*4 bytes (proven rounds 7-9).
    const size_t qElems   = (size_t)BB * NH * TT * HWP * CID;   // 6,422,528
    const size_t kElems   = (size_t)BB * NH * TP * HWP * CID;   // 8,028,160
    const size_t vtpElems = (size_t)BB * NH * TP * 64 * VSLOT;  // 9,175,040

    u16* Qw  = (u16*)d_ws;
    u16* Kw  = Qw + qElems;
    u16* Vtp = Kw + kElems;
    u16* Wb  = Vtp + vtpElems;
    u16* Xt  = (u16*)d_out;
    u16* Vpl = Xt + qElems;

    {
        const int wtot = NTOT * CC / 2;
        const int kper = 2 * NH * 8 * HWP * 32;
        const int vper = 2 * NH * 8 * 64 * (VSLOT / 2);
        prep_misc<<<(wtot + kper + vper + 255) / 256, 256, 0, stream>>>(
            Wq, Wk, Wv, Wb, bk, bv, Kw, Vtp);
    }
    transpose_x<<<BB * TT * 8, 256, 0, stream>>>(x, Xt);
    // 98 m-tiles (128 rows) x 6 n-tiles (256 cols), 512 threads = 8 waves
    proj_gemm2<<<98 * 6, 512, 0, stream>>>(Xt, Wb, bq, bk, bv, Qw, Kw, Vpl);
    v_reformat<<<BB * NH * TT, 256, 0, stream>>>(Vpl, Vtp);
    // 16 slabs * 32 t, 8 waves/block (frame-split g=0/1), XCD-swizzled;
    // 512 blocks = 2/CU -> 16 waves/CU (4/SIMD). Main loop barrier/LDS-free.
    attn_mfma4<<<512, 512, 0, stream>>>(x, Qw, Kw, Vtp, z);
}